// Round 1
// baseline (209.715 us; speedup 1.0000x reference)
//
#include <hip/hip_runtime.h>
#include <cstdint>

#define BB 8
#define CC 256
#define HH 128
#define WW 128
#define HW (HH * WW)
#define KK 49

// ---------------------------------------------------------------------------
// Kernel A: per-position channel mean & max of x -> y (B, 2, H, W) in d_ws
// One block per (b, h) row. 256 threads: 8 channel-groups x 32 float4 lanes.
// ---------------------------------------------------------------------------
__global__ __launch_bounds__(256) void reduce_meanmax(const float* __restrict__ x,
                                                      float* __restrict__ y) {
    const int bh = blockIdx.x;
    const int b  = bh >> 7;      // / HH
    const int h  = bh & 127;     // % HH
    const int t  = threadIdx.x;
    const int wq = t & 31;       // float4 column: w = wq*4
    const int cg = t >> 5;       // channel group 0..7 (32 channels each)

    const float* xb = x + ((size_t)(b * CC + cg * 32) * HH + h) * WW;

    float4 s = make_float4(0.f, 0.f, 0.f, 0.f);
    float4 m = make_float4(-INFINITY, -INFINITY, -INFINITY, -INFINITY);
    #pragma unroll 4
    for (int i = 0; i < 32; ++i) {
        float4 v = ((const float4*)(xb + (size_t)i * HW))[wq];
        s.x += v.x; s.y += v.y; s.z += v.z; s.w += v.w;
        m.x = fmaxf(m.x, v.x); m.y = fmaxf(m.y, v.y);
        m.z = fmaxf(m.z, v.z); m.w = fmaxf(m.w, v.w);
    }

    __shared__ float4 ls[8][32];
    __shared__ float4 lm[8][32];
    ls[cg][wq] = s;
    lm[cg][wq] = m;
    __syncthreads();

    if (t < 32) {
        float4 S = ls[0][t];
        float4 M = lm[0][t];
        #pragma unroll
        for (int g = 1; g < 8; ++g) {
            float4 a = ls[g][t];
            float4 c = lm[g][t];
            S.x += a.x; S.y += a.y; S.z += a.z; S.w += a.w;
            M.x = fmaxf(M.x, c.x); M.y = fmaxf(M.y, c.y);
            M.z = fmaxf(M.z, c.z); M.w = fmaxf(M.w, c.w);
        }
        const float inv = 1.0f / 256.0f;
        float4 mean = make_float4(S.x * inv, S.y * inv, S.z * inv, S.w * inv);
        float4* ym = (float4*)(y + ((size_t)(b * 2 + 0)) * HW + h * WW);
        float4* yx = (float4*)(y + ((size_t)(b * 2 + 1)) * HW + h * WW);
        ym[t] = mean;
        yx[t] = M;
    }
}

// ---------------------------------------------------------------------------
// Kernel B: fused 7x7 offset-conv + deformable bilinear sampling + BN+sigmoid
// gate, broadcast-written to out (B, C, H, W).
// One thread per spatial position. 98-value conv patch held in registers;
// weights are wave-uniform scalar loads.
// ---------------------------------------------------------------------------
__global__ __launch_bounds__(128) void deform_att(
    const float* __restrict__ y,
    const float* __restrict__ w_off, const float* __restrict__ b_off,
    const float* __restrict__ w_dcn, const float* __restrict__ b_dcn,
    const float* __restrict__ bn_gamma, const float* __restrict__ bn_beta,
    const float* __restrict__ bn_mean, const float* __restrict__ bn_var,
    float* __restrict__ out)
{
    const int bh = blockIdx.x;
    const int b  = bh >> 7;
    const int h  = bh & 127;
    const int w  = threadIdx.x;

    const float* ym = y + (size_t)(b * 2) * HW;      // mean plane
    const float* yx = ym + HW;                       // max plane

    // ---- load the 7x7x2 conv patch into registers (zero-padded) ----
    float p[98];
    #pragma unroll
    for (int ci = 0; ci < 2; ++ci) {
        const float* src = ci ? yx : ym;
        #pragma unroll
        for (int kr = 0; kr < 7; ++kr) {
            const int yy = h + kr - 3;
            const bool vy = (yy >= 0) && (yy < HH);
            const int cyy = min(max(yy, 0), HH - 1) * WW;
            #pragma unroll
            for (int kc = 0; kc < 7; ++kc) {
                const int xx = w + kc - 3;
                const bool v = vy && (xx >= 0) && (xx < WW);
                const int cxx = min(max(xx, 0), WW - 1);
                float val = src[cyy + cxx];
                p[ci * 49 + kr * 7 + kc] = v ? val : 0.0f;
            }
        }
    }

    const float bn_scale = bn_gamma[0] * rsqrtf(bn_var[0] + 1e-5f);

    float out_acc = 0.0f;
    int k = 0;
    for (int kr = 0; kr < 7; ++kr) {
        for (int kc = 0; kc < 7; ++kc, ++k) {
            // conv dot products for channels 2k (dy), 2k+1 (dx), 98+k (mask)
            const float* wY = w_off + (size_t)(2 * k) * 98;
            const float* wX = wY + 98;
            const float* wM = w_off + (size_t)(98 + k) * 98;
            float accY = b_off[2 * k];
            float accX = b_off[2 * k + 1];
            float accM = b_off[98 + k];
            #pragma unroll
            for (int j = 0; j < 98; ++j) {
                const float pj = p[j];
                accY = fmaf(wY[j], pj, accY);
                accX = fmaf(wX[j], pj, accX);
                accM = fmaf(wM[j], pj, accM);
            }

            const float mk = 1.0f / (1.0f + __expf(-accM));

            const float fy = (float)(h + kr - 3) + accY;
            const float fx = (float)(w + kc - 3) + accX;
            const float fly = floorf(fy), flx = floorf(fx);
            const int iy0 = (int)fly, ix0 = (int)flx;
            const int iy1 = iy0 + 1,  ix1 = ix0 + 1;
            const float wy1 = fy - fly, wy0 = 1.0f - wy1;
            const float wx1 = fx - flx, wx0 = 1.0f - wx1;

            const float vy0 = (iy0 >= 0 && iy0 < HH) ? 1.0f : 0.0f;
            const float vy1 = (iy1 >= 0 && iy1 < HH) ? 1.0f : 0.0f;
            const float vx0 = (ix0 >= 0 && ix0 < WW) ? 1.0f : 0.0f;
            const float vx1 = (ix1 >= 0 && ix1 < WW) ? 1.0f : 0.0f;

            const int cy0 = min(max(iy0, 0), HH - 1) * WW;
            const int cy1 = min(max(iy1, 0), HH - 1) * WW;
            const int cx0 = min(max(ix0, 0), WW - 1);
            const int cx1 = min(max(ix1, 0), WW - 1);

            const float w00 = wy0 * wx0 * vy0 * vx0;
            const float w01 = wy0 * wx1 * vy0 * vx1;
            const float w10 = wy1 * wx0 * vy1 * vx0;
            const float w11 = wy1 * wx1 * vy1 * vx1;

            const int i00 = cy0 + cx0, i01 = cy0 + cx1;
            const int i10 = cy1 + cx0, i11 = cy1 + cx1;

            const float v0 = ym[i00] * w00 + ym[i01] * w01 + ym[i10] * w10 + ym[i11] * w11;
            const float v1 = yx[i00] * w00 + yx[i01] * w01 + yx[i10] * w10 + yx[i11] * w11;

            out_acc = fmaf(mk, fmaf(v0, w_dcn[k], v1 * w_dcn[49 + k]), out_acc);
        }
    }

    float o = out_acc + b_dcn[0];
    o = (o - bn_mean[0]) * bn_scale + bn_beta[0];
    const float gate = 1.0f / (1.0f + __expf(-o));

    // ---- broadcast write across all 256 channels (coalesced in w) ----
    float* op = out + (size_t)(b * CC) * HW + h * WW + w;
    #pragma unroll 8
    for (int c = 0; c < CC; ++c) {
        op[(size_t)c * HW] = gate;
    }
}

extern "C" void kernel_launch(void* const* d_in, const int* in_sizes, int n_in,
                              void* d_out, int out_size, void* d_ws, size_t ws_size,
                              hipStream_t stream) {
    const float* x        = (const float*)d_in[0];
    const float* w_off    = (const float*)d_in[1];
    const float* b_off    = (const float*)d_in[2];
    const float* w_dcn    = (const float*)d_in[3];
    const float* b_dcn    = (const float*)d_in[4];
    const float* bn_gamma = (const float*)d_in[5];
    const float* bn_beta  = (const float*)d_in[6];
    const float* bn_mean  = (const float*)d_in[7];
    const float* bn_var   = (const float*)d_in[8];
    float* out = (float*)d_out;

    float* y = (float*)d_ws;   // (B, 2, H, W) = 1 MiB

    reduce_meanmax<<<BB * HH, 256, 0, stream>>>(x, y);
    deform_att<<<BB * HH, 128, 0, stream>>>(y, w_off, b_off, w_dcn, b_dcn,
                                            bn_gamma, bn_beta, bn_mean, bn_var,
                                            out);
}